// Round 2
// baseline (174.917 us; speedup 1.0000x reference)
//
#include <hip/hip_runtime.h>

// WaveConv3d: B=4, C=32, D=H=W=64, LEVEL=2, m=16.
// Stage 1: s[inp][k][b][c][v16] = (1/8) * WHT3( 2x2x2 sums of 4x4x4 block )
// Stage 2: mixed[k][b][o][v] = sum_i s1*W1 + s2*W2   (per-voxel 32x32 mixing)
// Stage 3: out = (1/8) * invWHT3(mixed) broadcast to 4x4x4 blocks

#define M3 4096        // 16*16*16 voxels
#define KS 524288      // 4*32*M3  : k-stride in s / mixed
#define IS 4194304     // 8*KS     : input-stride in s

// R1: force all 16 float4 loads into concurrently-live registers.
// R0 had VGPR_Count=32 -> loads fully serialized (1 in flight), 103us at
// 1.3 TB/s with VALUBusy 3.3%. launch_bounds(256,4) allows up to 128 VGPR
// (4 waves/SIMD guaranteed) so the f[16] array (64 VGPR) stays in registers
// and the wave issues 16 back-to-back global_load_dwordx4.
__global__ __launch_bounds__(256, 4) void k_fwd(const float* __restrict__ x1,
                                                const float* __restrict__ x2,
                                                float* __restrict__ s) {
  const int tid = blockIdx.x * 256 + threadIdx.x;   // 2*4*32*4096 threads
  const int v    = tid & 4095;
  const int rest = tid >> 12;        // inp*128 + b*32 + c
  const int c   = rest & 31;
  const int b   = (rest >> 5) & 3;
  const int inp = rest >> 7;
  const float* __restrict__ X = inp ? x2 : x1;
  const int z = v & 15, y = (v >> 4) & 15, x = v >> 8;
  const float* base =
      X + ((((size_t)(b * 32 + c) * 64 + 4 * x) * 64 + 4 * y) * 64 + 4 * z);

  float4 f[16];
#pragma unroll
  for (int dd = 0; dd < 4; ++dd)
#pragma unroll
    for (int hh = 0; hh < 4; ++hh)
      f[dd * 4 + hh] = *reinterpret_cast<const float4*>(base + (dd * 64 + hh) * 64);

  float blk[2][2][2] = {{{0.f, 0.f}, {0.f, 0.f}}, {{0.f, 0.f}, {0.f, 0.f}}};
#pragma unroll
  for (int dd = 0; dd < 4; ++dd) {
#pragma unroll
    for (int hh = 0; hh < 4; ++hh) {
      const float4 t = f[dd * 4 + hh];
      blk[dd >> 1][hh >> 1][0] += t.x + t.y;
      blk[dd >> 1][hh >> 1][1] += t.z + t.w;
    }
  }
  // 8-point Walsh-Hadamard over m = p*4+q*2+r; s[k] = (1/8) sum_m (-1)^pc(k&m) blk[m]
  const float a0 = blk[0][0][0], a1 = blk[0][0][1], a2 = blk[0][1][0], a3 = blk[0][1][1];
  const float a4 = blk[1][0][0], a5 = blk[1][0][1], a6 = blk[1][1][0], a7 = blk[1][1][1];
  const float t0 = a0 + a1, t1 = a0 - a1, t2 = a2 + a3, t3 = a2 - a3;
  const float t4 = a4 + a5, t5 = a4 - a5, t6 = a6 + a7, t7 = a6 - a7;
  const float u0 = t0 + t2, u2 = t0 - t2, u1 = t1 + t3, u3 = t1 - t3;
  const float u4 = t4 + t6, u6 = t4 - t6, u5 = t5 + t7, u7 = t5 - t7;
  float* o = s + (size_t)inp * IS + (size_t)(b * 32 + c) * M3 + v;
  o[0 * KS] = 0.125f * (u0 + u4);
  o[4 * KS] = 0.125f * (u0 - u4);
  o[1 * KS] = 0.125f * (u1 + u5);
  o[5 * KS] = 0.125f * (u1 - u5);
  o[2 * KS] = 0.125f * (u2 + u6);
  o[6 * KS] = 0.125f * (u2 - u6);
  o[3 * KS] = 0.125f * (u3 + u7);
  o[7 * KS] = 0.125f * (u3 - u7);
}

__global__ __launch_bounds__(256) void k_mix(const float* __restrict__ W1,
                                             const float* __restrict__ W2,
                                             const float* __restrict__ s,
                                             float* __restrict__ mixed) {
  // 512 blocks: k = bid%8 (XCD-pinned so each subband's 4MiB s-slice stays in one L2)
  const int bid  = blockIdx.x;
  const int k    = bid & 7;
  const int rest = bid >> 3;       // og(4) x vblk(16)
  const int og   = rest & 3;
  const int vblk = rest >> 2;
  const int v = vblk * 256 + threadIdx.x;
  const float* pW1 = W1 + ((size_t)k * 1024 + og * 8) * M3 + v;
  const float* pW2 = W2 + ((size_t)k * 1024 + og * 8) * M3 + v;
  const float* ps  = s + (size_t)k * KS + v;
  float acc[4][8];
#pragma unroll
  for (int b = 0; b < 4; ++b)
#pragma unroll
    for (int oo = 0; oo < 8; ++oo) acc[b][oo] = 0.f;
#pragma unroll 2
  for (int i = 0; i < 32; ++i) {
    float s1b[4], s2b[4];
#pragma unroll
    for (int b = 0; b < 4; ++b) {
      s1b[b] = ps[(size_t)(b * 32 + i) * M3];
      s2b[b] = ps[(size_t)IS + (size_t)(b * 32 + i) * M3];
    }
#pragma unroll
    for (int oo = 0; oo < 8; ++oo) {
      const float w1 = pW1[(size_t)(i * 32 + oo) * M3];
      const float w2 = pW2[(size_t)(i * 32 + oo) * M3];
#pragma unroll
      for (int b = 0; b < 4; ++b) acc[b][oo] += s1b[b] * w1 + s2b[b] * w2;
    }
  }
  float* pm = mixed + (size_t)k * KS + (size_t)og * 8 * M3 + v;
#pragma unroll
  for (int b = 0; b < 4; ++b)
#pragma unroll
    for (int oo = 0; oo < 8; ++oo)
      pm[(size_t)b * (32 * M3) + (size_t)oo * M3] = acc[b][oo];
}

__global__ __launch_bounds__(256) void k_inv(const float* __restrict__ mixed,
                                             float* __restrict__ out) {
  const int tid = blockIdx.x * 256 + threadIdx.x;  // 4*32*4096 threads
  const int v = tid & 4095;
  const int o = (tid >> 12) & 31;
  const int b = tid >> 17;
  const float* pm = mixed + (size_t)(b * 32 + o) * M3 + v;
  const float m0 = pm[0 * (size_t)KS], m1 = pm[1 * (size_t)KS];
  const float m2 = pm[2 * (size_t)KS], m3 = pm[3 * (size_t)KS];
  const float m4 = pm[4 * (size_t)KS], m5 = pm[5 * (size_t)KS];
  const float m6 = pm[6 * (size_t)KS], m7 = pm[7 * (size_t)KS];
  const float t0 = m0 + m1, t1 = m0 - m1, t2 = m2 + m3, t3 = m2 - m3;
  const float t4 = m4 + m5, t5 = m4 - m5, t6 = m6 + m7, t7 = m6 - m7;
  const float u0 = t0 + t2, u2 = t0 - t2, u1 = t1 + t3, u3 = t1 - t3;
  const float u4 = t4 + t6, u6 = t4 - t6, u5 = t5 + t7, u7 = t5 - t7;
  float w[2][2][2];  // w[p][q][r], m = p*4+q*2+r, includes the 1/8
  w[0][0][0] = 0.125f * (u0 + u4);
  w[1][0][0] = 0.125f * (u0 - u4);
  w[0][0][1] = 0.125f * (u1 + u5);
  w[1][0][1] = 0.125f * (u1 - u5);
  w[0][1][0] = 0.125f * (u2 + u6);
  w[1][1][0] = 0.125f * (u2 - u6);
  w[0][1][1] = 0.125f * (u3 + u7);
  w[1][1][1] = 0.125f * (u3 - u7);
  const int z = v & 15, y = (v >> 4) & 15, x = v >> 8;
  float* base =
      out + ((((size_t)(b * 32 + o) * 64 + 4 * x) * 64 + 4 * y) * 64 + 4 * z);
#pragma unroll
  for (int dd = 0; dd < 4; ++dd) {
    const int p = dd >> 1;
#pragma unroll
    for (int hh = 0; hh < 4; ++hh) {
      const int q = hh >> 1;
      const float lo = w[p][q][0], hi = w[p][q][1];
      float4 f;
      f.x = lo; f.y = lo; f.z = hi; f.w = hi;
      *reinterpret_cast<float4*>(base + (dd * 64 + hh) * 64) = f;
    }
  }
}

extern "C" void kernel_launch(void* const* d_in, const int* in_sizes, int n_in,
                              void* d_out, int out_size, void* d_ws, size_t ws_size,
                              hipStream_t stream) {
  const float* x1 = (const float*)d_in[0];
  const float* x2 = (const float*)d_in[1];
  const float* W1 = (const float*)d_in[2];
  const float* W2 = (const float*)d_in[3];
  float* out = (float*)d_out;
  float* s     = (float*)d_ws;             // 2*IS floats = 32 MiB
  float* mixed = s + 2 * (size_t)IS;       // IS floats   = 16 MiB
  k_fwd<<<4096, 256, 0, stream>>>(x1, x2, s);
  k_mix<<<512, 256, 0, stream>>>(W1, W2, s, mixed);
  k_inv<<<2048, 256, 0, stream>>>(mixed, out);
}

// Round 4
// 167.441 us; speedup vs baseline: 1.0446x; 1.0446x over previous
//
#include <hip/hip_runtime.h>

// WaveConv3d: B=4, C=32, D=H=W=64, LEVEL=2, m=16.
// Stage 1: s[inp][k][b][c][v16] = (1/8) * WHT3( 2x2x2 sums of 4x4x4 block )
// Stage 2: mixed[k][b][o][v] = sum_i s1*W1 + s2*W2   (per-voxel 32x32 mixing)
// Stage 3: out = (1/8) * invWHT3(mixed) broadcast to 4x4x4 blocks

#define M3 4096        // 16*16*16 voxels
#define KS 524288      // 4*32*M3  : k-stride in s / mixed
#define IS 4194304     // 8*KS     : input-stride in s

// R3: R2 structure with the OOB fix (slab offset xsl*16384 floats, NOT 65536
// -- that was a bytes/floats confusion that page-faulted) plus z-dim pad
// 16->17 in LDS to kill a 4-way read bank conflict in stage 2.
//  Structure: block = (inp,b,c,x-slab). The slab (4 d-planes x 64 x 64) is
//  CONTIGUOUS 64KB; 256 threads read it with 16 linear float4 each, pinned
//  before use by sched_barrier(0) so all 16 loads are in flight. Then
//  2-stage LDS reduce: float2 z-pair partials -> per-(y,z) thread gathers
//  4d x 4h partials, 8-pt WHT, 8 coalesced stores.
__global__ __launch_bounds__(256, 4) void k_fwd(const float* __restrict__ x1,
                                                const float* __restrict__ x2,
                                                float* __restrict__ s) {
  const int bid  = blockIdx.x;       // 2*128*16 = 4096 blocks
  const int xsl  = bid & 15;         // x slab index (d-planes 4*xsl..4*xsl+3)
  const int rest = bid >> 4;
  const int bc   = rest & 127;       // b*32+c
  const int inp  = rest >> 7;
  const float* __restrict__ X =
      (inp ? x2 : x1) + (size_t)bc * 262144 + (size_t)xsl * 16384;

  const int tid = threadIdx.x;
  __shared__ float part[4 * 64 * 17 * 2];  // [d][h][zpad17][r], 34 KB

  // ---- stage 0: 16 linear float4 loads, all in flight ----
  float4 f[16];
#pragma unroll
  for (int j = 0; j < 16; ++j)
    f[j] = *reinterpret_cast<const float4*>(X + j * 1024 + tid * 4);
  __builtin_amdgcn_sched_barrier(0);   // do NOT sink loads into the use loop

  // ---- stage 1: z-pair partial sums -> LDS ----
#pragma unroll
  for (int j = 0; j < 16; ++j) {
    const int idx = j * 1024 + tid * 4;        // float index within slab
    const int d = idx >> 12;                   // 0..3
    const int h = (idx >> 6) & 63;             // 0..63
    const int z = (idx & 63) >> 2;             // 0..15
    float2 pr;
    pr.x = f[j].x + f[j].y;                    // r=0 (w pair 0)
    pr.y = f[j].z + f[j].w;                    // r=1 (w pair 1)
    *reinterpret_cast<float2*>(&part[((d * 64 + h) * 17 + z) * 2]) = pr;
  }
  __syncthreads();

  // ---- stage 2: thread per (y,z): gather 4d x 4h partials, WHT, store ----
  const int z = tid & 15, y = tid >> 4;
  float blk[2][2][2] = {{{0.f, 0.f}, {0.f, 0.f}}, {{0.f, 0.f}, {0.f, 0.f}}};
#pragma unroll
  for (int p = 0; p < 2; ++p)
#pragma unroll
    for (int dd = 0; dd < 2; ++dd)
#pragma unroll
      for (int q = 0; q < 2; ++q)
#pragma unroll
        for (int hh = 0; hh < 2; ++hh) {
          const float2 pr = *reinterpret_cast<const float2*>(
              &part[(((2 * p + dd) * 64 + (4 * y + 2 * q + hh)) * 17 + z) * 2]);
          blk[p][q][0] += pr.x;
          blk[p][q][1] += pr.y;
        }
  const float a0 = blk[0][0][0], a1 = blk[0][0][1], a2 = blk[0][1][0], a3 = blk[0][1][1];
  const float a4 = blk[1][0][0], a5 = blk[1][0][1], a6 = blk[1][1][0], a7 = blk[1][1][1];
  const float t0 = a0 + a1, t1 = a0 - a1, t2 = a2 + a3, t3 = a2 - a3;
  const float t4 = a4 + a5, t5 = a4 - a5, t6 = a6 + a7, t7 = a6 - a7;
  const float u0 = t0 + t2, u2 = t0 - t2, u1 = t1 + t3, u3 = t1 - t3;
  const float u4 = t4 + t6, u6 = t4 - t6, u5 = t5 + t7, u7 = t5 - t7;
  float* o = s + (size_t)inp * IS + (size_t)bc * M3 + xsl * 256 + y * 16 + z;
  o[0 * KS] = 0.125f * (u0 + u4);
  o[4 * KS] = 0.125f * (u0 - u4);
  o[1 * KS] = 0.125f * (u1 + u5);
  o[5 * KS] = 0.125f * (u1 - u5);
  o[2 * KS] = 0.125f * (u2 + u6);
  o[6 * KS] = 0.125f * (u2 - u6);
  o[3 * KS] = 0.125f * (u3 + u7);
  o[7 * KS] = 0.125f * (u3 - u7);
}

__global__ __launch_bounds__(256) void k_mix(const float* __restrict__ W1,
                                             const float* __restrict__ W2,
                                             const float* __restrict__ s,
                                             float* __restrict__ mixed) {
  // 512 blocks: k = bid%8 (XCD-pinned so each subband's 4MiB s-slice stays in one L2)
  const int bid  = blockIdx.x;
  const int k    = bid & 7;
  const int rest = bid >> 3;       // og(4) x vblk(16)
  const int og   = rest & 3;
  const int vblk = rest >> 2;
  const int v = vblk * 256 + threadIdx.x;
  const float* pW1 = W1 + ((size_t)k * 1024 + og * 8) * M3 + v;
  const float* pW2 = W2 + ((size_t)k * 1024 + og * 8) * M3 + v;
  const float* ps  = s + (size_t)k * KS + v;
  float acc[4][8];
#pragma unroll
  for (int b = 0; b < 4; ++b)
#pragma unroll
    for (int oo = 0; oo < 8; ++oo) acc[b][oo] = 0.f;
#pragma unroll 2
  for (int i = 0; i < 32; ++i) {
    float s1b[4], s2b[4];
#pragma unroll
    for (int b = 0; b < 4; ++b) {
      s1b[b] = ps[(size_t)(b * 32 + i) * M3];
      s2b[b] = ps[(size_t)IS + (size_t)(b * 32 + i) * M3];
    }
#pragma unroll
    for (int oo = 0; oo < 8; ++oo) {
      const float w1 = pW1[(size_t)(i * 32 + oo) * M3];
      const float w2 = pW2[(size_t)(i * 32 + oo) * M3];
#pragma unroll
      for (int b = 0; b < 4; ++b) acc[b][oo] += s1b[b] * w1 + s2b[b] * w2;
    }
  }
  float* pm = mixed + (size_t)k * KS + (size_t)og * 8 * M3 + v;
#pragma unroll
  for (int b = 0; b < 4; ++b)
#pragma unroll
    for (int oo = 0; oo < 8; ++oo)
      pm[(size_t)b * (32 * M3) + (size_t)oo * M3] = acc[b][oo];
}

__global__ __launch_bounds__(256) void k_inv(const float* __restrict__ mixed,
                                             float* __restrict__ out) {
  const int tid = blockIdx.x * 256 + threadIdx.x;  // 4*32*4096 threads
  const int v = tid & 4095;
  const int o = (tid >> 12) & 31;
  const int b = tid >> 17;
  const float* pm = mixed + (size_t)(b * 32 + o) * M3 + v;
  const float m0 = pm[0 * (size_t)KS], m1 = pm[1 * (size_t)KS];
  const float m2 = pm[2 * (size_t)KS], m3 = pm[3 * (size_t)KS];
  const float m4 = pm[4 * (size_t)KS], m5 = pm[5 * (size_t)KS];
  const float m6 = pm[6 * (size_t)KS], m7 = pm[7 * (size_t)KS];
  const float t0 = m0 + m1, t1 = m0 - m1, t2 = m2 + m3, t3 = m2 - m3;
  const float t4 = m4 + m5, t5 = m4 - m5, t6 = m6 + m7, t7 = m6 - m7;
  const float u0 = t0 + t2, u2 = t0 - t2, u1 = t1 + t3, u3 = t1 - t3;
  const float u4 = t4 + t6, u6 = t4 - t6, u5 = t5 + t7, u7 = t5 - t7;
  float w[2][2][2];  // w[p][q][r], m = p*4+q*2+r, includes the 1/8
  w[0][0][0] = 0.125f * (u0 + u4);
  w[1][0][0] = 0.125f * (u0 - u4);
  w[0][0][1] = 0.125f * (u1 + u5);
  w[1][0][1] = 0.125f * (u1 - u5);
  w[0][1][0] = 0.125f * (u2 + u6);
  w[1][1][0] = 0.125f * (u2 - u6);
  w[0][1][1] = 0.125f * (u3 + u7);
  w[1][1][1] = 0.125f * (u3 - u7);
  const int z = v & 15, y = (v >> 4) & 15, x = v >> 8;
  float* base =
      out + ((((size_t)(b * 32 + o) * 64 + 4 * x) * 64 + 4 * y) * 64 + 4 * z);
#pragma unroll
  for (int dd = 0; dd < 4; ++dd) {
    const int p = dd >> 1;
#pragma unroll
    for (int hh = 0; hh < 4; ++hh) {
      const int q = hh >> 1;
      const float lo = w[p][q][0], hi = w[p][q][1];
      float4 f;
      f.x = lo; f.y = lo; f.z = hi; f.w = hi;
      *reinterpret_cast<float4*>(base + (dd * 64 + hh) * 64) = f;
    }
  }
}

extern "C" void kernel_launch(void* const* d_in, const int* in_sizes, int n_in,
                              void* d_out, int out_size, void* d_ws, size_t ws_size,
                              hipStream_t stream) {
  const float* x1 = (const float*)d_in[0];
  const float* x2 = (const float*)d_in[1];
  const float* W1 = (const float*)d_in[2];
  const float* W2 = (const float*)d_in[3];
  float* out = (float*)d_out;
  float* s     = (float*)d_ws;             // 2*IS floats = 32 MiB
  float* mixed = s + 2 * (size_t)IS;       // IS floats   = 16 MiB
  k_fwd<<<4096, 256, 0, stream>>>(x1, x2, s);
  k_mix<<<512, 256, 0, stream>>>(W1, W2, s, mixed);
  k_inv<<<2048, 256, 0, stream>>>(mixed, out);
}